// Round 15
// baseline (2231.092 us; speedup 1.0000x reference)
//
#include <hip/hip_runtime.h>

#define N_USERS 20000
#define N_ITEMS 20000
#define NI1     20001      // row stride (elements) of interactions
#define HB      4096       // batch
#define H0      256
#define H1      512
#define H2      256
#define PKW     632        // u32 words per packed row (625 data + 7 zero pad)
#define PKB     (PKW*4)    // 2528 bytes per packed row
#define NWF     12501251   // flat words: ceil(20001*20001 / 32)

typedef unsigned short u16;
typedef unsigned char  u8;
typedef unsigned int   u32;
typedef unsigned long long u64;

typedef __attribute__((ext_vector_type(8))) __bf16 bf16x8;
typedef __attribute__((ext_vector_type(4))) float  f32x4;

__device__ __forceinline__ u16 f2bf(float f) {
  u32 u = __float_as_uint(f);
  u32 r = (u + 0x7FFFu + ((u >> 16) & 1u)) >> 16;   // RNE
  return (u16)r;
}

// ---------------- detect interactions element layout ----------------
__global__ __launch_bounds__(256) void k_detect(const u8* __restrict__ inter,
                                                int* __restrict__ flag) {
  __shared__ u32 cnt[4];
  if (threadIdx.x < 4) cnt[threadIdx.x] = 0;
  __syncthreads();
  u32 loc0 = 0, loc1 = 0, loc2 = 0, loc3 = 0;
  for (int i = threadIdx.x; i < 16384; i += 256) {   // 64 KB scan
    u32 w = ((const u32*)inter)[i];
    loc0 += (w & 0x000000FFu) ? 1u : 0u;
    loc1 += (w & 0x0000FF00u) ? 1u : 0u;
    loc2 += (w & 0x00FF0000u) ? 1u : 0u;
    loc3 += (w & 0xFF000000u) ? 1u : 0u;
  }
  atomicAdd(&cnt[0], loc0); atomicAdd(&cnt[1], loc1);
  atomicAdd(&cnt[2], loc2); atomicAdd(&cnt[3], loc3);
  __syncthreads();
  if (threadIdx.x == 0) {
    int lay;
    if (cnt[1] != 0)      lay = 0;
    else if (cnt[0] != 0) lay = 1;
    else                  lay = 2;
    *flag = lay;
  }
}

// ---------------- flat bit-pack, wave-coalesced (INSTRUMENTED rep x4) ----------------
__global__ __launch_bounds__(256) void k_packF(const u8* __restrict__ inter,
                                               u32* __restrict__ pkF,
                                               const int* __restrict__ flag) {
  int lay = *flag;
  __shared__ u32 nibs[4][8][64];
  const size_t TE = (size_t)NI1 * NI1;
  const int NG = (int)((TE + 8191) / 8192);
  int wave = threadIdx.x >> 6, lane = threadIdx.x & 63;
  const u32* base32 = (const u32*)inter;
  for (int rep = 0; rep < 4; ++rep) {
  for (int g = blockIdx.x; g < NG; g += gridDim.x) {
    size_t E0 = (size_t)g * 8192 + (size_t)wave * 2048;
    bool full = ((size_t)(g + 1) * 8192) <= TE;
    if (lay != 0) {
      if (full) {
        #pragma unroll
        for (int t = 0; t < 8; ++t) {
          size_t e = E0 + (size_t)t * 256 + lane * 4;
          uint4 v = *(const uint4*)(base32 + e);
          nibs[wave][t][lane] = (v.x ? 1u : 0u) | (v.y ? 2u : 0u) |
                                (v.z ? 4u : 0u) | (v.w ? 8u : 0u);
        }
      } else {
        #pragma unroll
        for (int t = 0; t < 8; ++t) {
          size_t e = E0 + (size_t)t * 256 + lane * 4;
          u32 n = 0;
          #pragma unroll
          for (int c = 0; c < 4; ++c)
            if (e + c < TE && base32[e + c]) n |= 1u << c;
          nibs[wave][t][lane] = n;
        }
      }
    } else {
      #pragma unroll
      for (int t = 0; t < 8; ++t) {
        size_t e = E0 + (size_t)t * 256 + lane * 4;
        u32 n = 0;
        #pragma unroll
        for (int c = 0; c < 4; ++c)
          if (e + c < TE && inter[e + c]) n |= 1u << c;
        nibs[wave][t][lane] = n;
      }
    }
    __syncthreads();
    {
      int t = lane >> 3, j = lane & 7;
      u32 wrd = 0;
      #pragma unroll
      for (int k = 0; k < 8; ++k) wrd |= nibs[wave][t][8 * j + k] << (4 * k);
      size_t wg = (size_t)g * 256 + wave * 64 + lane;
      if (wg < NWF) pkF[wg] = wrd;
    }
    __syncthreads();
  }
  }
}

// ---------------- realign: pk[r][w] = flat bits [r*20001 + w*32, +32) ----------------
__global__ __launch_bounds__(256) void k_realign(const u32* __restrict__ pkF,
                                                 u32* __restrict__ pk) {
  int r = blockIdx.x;
  int base = 625 * r + (r >> 5);
  int s = r & 31;
  for (int w = threadIdx.x; w < PKW; w += 256) {
    u32 val = 0;
    if (w < 625) {
      u32 lo = pkF[base + w];
      u32 hi = pkF[base + w + 1];
      val = s ? ((lo >> s) | (hi << (32 - s))) : lo;
    }
    pk[(size_t)r * PKW + w] = val;
  }
}

// ---------------- bit transpose (INSTRUMENTED rep x16) ----------------
#define HDSTEP(J, M)                                      \
  _Pragma("unroll")                                       \
  for (int k = 0; k < 32; ++k) if (!(k & J)) {            \
    u32 tt = (a[k] ^ (a[k | J] >> J)) & M;                \
    a[k] ^= tt; a[k | J] ^= tt << J;                      \
  }

__global__ __launch_bounds__(256) void k_bitT(const u32* __restrict__ pk,
                                              u32* __restrict__ pkT) {
  __shared__ u32 in_l[512][17];
  __shared__ u32 out_l[32][16][17];
  int t = threadIdx.x;
  int vt = blockIdx.x % 40, wt = blockIdx.x / 40;
  int v0 = vt * 16, wc0 = wt * 16;
  int lw = t & 15, lr = t >> 4;
  for (int rep = 0; rep < 16; ++rep) {
  for (int ch = 0; ch < 32; ++ch) {
    int rloc = ch * 16 + lr;
    int R = v0 * 32 + rloc;
    int W = wc0 + lw;
    u32 val = 0;
    if (R < N_USERS && W < PKW) val = pk[(size_t)R * PKW + W];
    in_l[rloc][lw] = val;
  }
  __syncthreads();
  u32 a[32];
  #pragma unroll
  for (int j = 0; j < 32; ++j) a[j] = in_l[lr * 32 + j][lw];
  HDSTEP(16, 0x0000FFFFu)
  HDSTEP(8,  0x00FF00FFu)
  HDSTEP(4,  0x0F0F0F0Fu)
  HDSTEP(2,  0x33333333u)
  HDSTEP(1,  0x55555555u)
  #pragma unroll
  for (int i = 0; i < 32; ++i) out_l[i][lw][lr] = __brev(a[31 - i]);
  __syncthreads();
  for (int ch = 0; ch < 32; ++ch) {
    int rloc = ch * 16 + lr;
    int C = wc0 * 32 + rloc;
    int V = v0 + lw;
    if (C < N_ITEMS && V < PKW)
      pkT[(size_t)C * PKW + V] = out_l[rloc & 31][rloc >> 5][lw];
  }
  __syncthreads();
  }
}

// ---------------- f32 -> bf16 for Wu and Wi in one launch ----------------
__global__ __launch_bounds__(256) void k_convert2(const float* __restrict__ Wu,
                                                  const float* __restrict__ Wi,
                                                  u16* __restrict__ Wub,
                                                  u16* __restrict__ Wib) {
  const int n4 = H0 * N_ITEMS / 4;
  int stride = gridDim.x * 256;
  for (int i = blockIdx.x * 256 + threadIdx.x; i < 2 * n4; i += stride) {
    const float* in = (i < n4) ? Wu : Wi;
    u16* out = (i < n4) ? Wub : Wib;
    int idx = (i < n4) ? i : i - n4;
    float4 v = ((const float4*)in)[idx];
    u64 p = (u64)f2bf(v.x) | ((u64)f2bf(v.y) << 16) |
            ((u64)f2bf(v.z) << 32) | ((u64)f2bf(v.w) << 48);
    ((u64*)out)[idx] = p;
  }
}

// ---------------- f32 transpose for W1 and W2 in one launch ----------------
__global__ __launch_bounds__(256) void k_transpose2(const float* __restrict__ W1,
                                                    float* __restrict__ W1T,
                                                    const float* __restrict__ W2,
                                                    float* __restrict__ W2T) {
  __shared__ float tile[32][33];
  int bid = blockIdx.x;
  const float* in; float* out; int R, C, b;
  if (bid < 128) { in = W1; out = W1T; R = H1; C = H0; b = bid; }
  else           { in = W2; out = W2T; R = H2; C = H1; b = bid - 128; }
  int nbx = C >> 5;
  int bx = b % nbx, by = b / nbx;
  int c0 = bx * 32, r0 = by * 32;
  int lx = threadIdx.x & 31, ly = threadIdx.x >> 5;
  #pragma unroll
  for (int j = 0; j < 4; ++j)
    tile[ly + 8*j][lx] = in[(size_t)(r0 + ly + 8*j) * C + c0 + lx];
  __syncthreads();
  #pragma unroll
  for (int j = 0; j < 4; ++j)
    out[(size_t)(c0 + ly + 8*j) * R + r0 + lx] = tile[lx][ly + 8*j];
}

// ---------------- counting sort of batch rows by item_idx ----------------
__global__ __launch_bounds__(1024) void k_sort(const int* __restrict__ item_idx,
                                               int* __restrict__ perm) {
  __shared__ u32 cnt[N_ITEMS];     // 80 KB
  __shared__ u32 tsum[1024];
  int t = threadIdx.x;
  for (int i = t; i < N_ITEMS; i += 1024) cnt[i] = 0;
  __syncthreads();
  for (int b = t; b < HB; b += 1024) atomicAdd(&cnt[item_idx[b]], 1u);
  __syncthreads();
  u32 s = 0;
  int base = t * 20;
  for (int j = 0; j < 20; ++j) { int i = base + j; if (i < N_ITEMS) s += cnt[i]; }
  tsum[t] = s;
  __syncthreads();
  for (int off = 1; off < 1024; off <<= 1) {
    u32 v = (t >= off) ? tsum[t - off] : 0u;
    __syncthreads();
    tsum[t] += v;
    __syncthreads();
  }
  u32 run = tsum[t] - s;  // exclusive prefix
  for (int j = 0; j < 20; ++j) {
    int i = base + j;
    if (i < N_ITEMS) { u32 c = cnt[i]; cnt[i] = run; run += c; }
  }
  __syncthreads();
  for (int b = t; b < HB; b += 1024) {
    int v = item_idx[b];
    u32 pos = atomicAdd(&cnt[v], 1u);
    perm[pos] = b;
  }
}

// ---------------- packed-bit GEMM: dbuf B + A/B prefetch pipeline ----------------
__global__ __launch_bounds__(256, 4) void k_gemm(
    const u32* __restrict__ pk, const u32* __restrict__ pkT,
    const int* __restrict__ user_idx, const int* __restrict__ item_idx,
    const int* __restrict__ perm,
    const u16* __restrict__ Wub, const u16* __restrict__ Wib,
    float* __restrict__ u0, float* __restrict__ u0b,
    float* __restrict__ ir, float* __restrict__ irb) {
  __shared__ __attribute__((aligned(16))) u16 Bls[2][32 * 256];  // 2 x 16 KB
  __shared__ __attribute__((aligned(16))) uint2 lut8[16];        // nibble -> 4 bf16
  __shared__ u32 pbase[128];
  __shared__ int prow[128];

  int bid = blockIdx.x;
  int kh = bid >> 9;
  int mode_item = (bid >> 8) & 1;
  int lid = bid & 255;
  int M0 = (lid >> 3) * 128;
  int N0 = (lid & 7) * 32;
  int tid = threadIdx.x;
  const u16* Wb = mode_item ? Wib : Wub;
  const u8* Pk = (const u8*)(mode_item ? pkT : pk);
  float* Cout = mode_item ? (kh ? irb : ir) : (kh ? u0b : u0);

  if (tid < 16) {
    u32 v = tid;
    lut8[tid].x = ((v & 1u) ? 0x3F80u : 0u) | ((v & 2u) ? 0x3F800000u : 0u);
    lut8[tid].y = ((v & 4u) ? 0x3F80u : 0u) | ((v & 8u) ? 0x3F800000u : 0u);
  }
  if (tid < 128) {
    int s = M0 + tid;
    if (mode_item) { int p = perm[s]; prow[tid] = p; pbase[tid] = (u32)item_idx[p] * PKB; }
    else           { prow[tid] = s;   pbase[tid] = (u32)user_idx[s] * PKB; }
  }
  __syncthreads();

  f32x4 acc[2][2];
  #pragma unroll
  for (int a = 0; a < 2; ++a)
    #pragma unroll
    for (int b = 0; b < 2; ++b)
      #pragma unroll
      for (int j = 0; j < 4; ++j) acc[a][b][j] = 0.f;

  int lane = tid & 63, wave = tid >> 6;
  int WM = wave * 32;
  int lrow = lane & 15;
  int lk8 = lane >> 4;            // 0..3
  int sh = lk8 * 8;

  u32 pb0 = pbase[WM + lrow];
  u32 pb1 = pbase[WM + 16 + lrow];

  int bsn[4], bsk[4], bso[4];
  #pragma unroll
  for (int i = 0; i < 4; ++i) {
    int id = tid + 256 * i;
    int n = id >> 5, c8 = id & 31;
    bsn[i] = N0 + n;
    bsk[i] = c8 * 8;
    bso[i] = n * 256 + ((c8 * 8) ^ ((n & 7) << 3));
  }

  int k0_beg = kh ? 10240 : 0;
  int k0_end = kh ? 20224 : 10240;   // 40/39 iters; bit pad >=20000 is zero

  uint4 breg[4];
  #pragma unroll
  for (int i = 0; i < 4; ++i) {
    int k = k0_beg + bsk[i];
    breg[i] = make_uint4(0u, 0u, 0u, 0u);
    if (k < N_ITEMS) breg[i] = *(const uint4*)&Wb[(size_t)bsn[i] * N_ITEMS + k];
  }
  #pragma unroll
  for (int i = 0; i < 4; ++i) *(uint4*)&Bls[0][bso[i]] = breg[i];
  int bc0 = k0_beg >> 3;
  uint4 ca0l = *(const uint4*)(Pk + pb0 + bc0);
  uint4 ca0h = *(const uint4*)(Pk + pb0 + bc0 + 16);
  uint4 ca1l = *(const uint4*)(Pk + pb1 + bc0);
  uint4 ca1h = *(const uint4*)(Pk + pb1 + bc0 + 16);
  __syncthreads();

  int cur = 0;
  for (int k0 = k0_beg; k0 < k0_end; k0 += 256) {
    int k1 = k0 + 256;
    bool more = k1 < k0_end;
    uint4 na0l, na0h, na1l, na1h;
    if (more) {
      #pragma unroll
      for (int i = 0; i < 4; ++i) {
        int k = k1 + bsk[i];
        breg[i] = make_uint4(0u, 0u, 0u, 0u);
        if (k < N_ITEMS) breg[i] = *(const uint4*)&Wb[(size_t)bsn[i] * N_ITEMS + k];
      }
      int nbc = k1 >> 3;
      na0l = *(const uint4*)(Pk + pb0 + nbc);
      na0h = *(const uint4*)(Pk + pb0 + nbc + 16);
      na1l = *(const uint4*)(Pk + pb1 + nbc);
      na1h = *(const uint4*)(Pk + pb1 + nbc + 16);
    }
    u32 qw0[8] = {ca0l.x, ca0l.y, ca0l.z, ca0l.w, ca0h.x, ca0h.y, ca0h.z, ca0h.w};
    u32 qw1[8] = {ca1l.x, ca1l.y, ca1l.z, ca1l.w, ca1h.x, ca1h.y, ca1h.z, ca1h.w};
    #pragma unroll
    for (int kki = 0; kki < 8; ++kki) {
      u32 b0 = (qw0[kki] >> sh) & 0xFFu;
      u32 b1 = (qw1[kki] >> sh) & 0xFFu;
      union { u32 w[4]; bf16x8 v; } a0, a1;
      uint2 l0 = lut8[b0 & 15u], h0 = lut8[b0 >> 4];
      uint2 l1 = lut8[b1 & 15u], h1 = lut8[b1 >> 4];
      a0.w[0] = l0.x; a0.w[1] = l0.y; a0.w[2] = h0.x; a0.w[3] = h0.y;
      a1.w[0] = l1.x; a1.w[1] = l1.y; a1.w[2] = h1.x; a1.w[3] = h1.y;
      bf16x8 bfr[2];
      #pragma unroll
      for (int fn = 0; fn < 2; ++fn) {
        int n = fn * 16 + lrow;
        bfr[fn] = *(const bf16x8*)&Bls[cur][n * 256 + ((kki * 32 + sh) ^ ((n & 7) << 3))];
      }
      acc[0][0] = __builtin_amdgcn_mfma_f32_16x16x32_bf16(a0.v, bfr[0], acc[0][0], 0, 0, 0);
      acc[0][1] = __builtin_amdgcn_mfma_f32_16x16x32_bf16(a0.v, bfr[1], acc[0][1], 0, 0, 0);
      acc[1][0] = __builtin_amdgcn_mfma_f32_16x16x32_bf16(a1.v, bfr[0], acc[1][0], 0, 0, 0);
      acc[1][1] = __builtin_amdgcn_mfma_f32_16x16x32_bf16(a1.v, bfr[1], acc[1][1], 0, 0, 0);
    }
    if (more) {
      #pragma unroll
      for (int i = 0; i < 4; ++i) *(uint4*)&Bls[cur ^ 1][bso[i]] = breg[i];
      ca0l = na0l; ca0h = na0h; ca1l = na1l; ca1h = na1h;
    }
    __syncthreads();
    cur ^= 1;
  }

  int crow0 = (lane >> 4) * 4;
  int ccol = lane & 15;
  #pragma unroll
  for (int fm = 0; fm < 2; ++fm)
    #pragma unroll
    for (int fn = 0; fn < 2; ++fn) {
      f32x4 v = acc[fm][fn];
      int col = N0 + fn * 16 + ccol;
      #pragma unroll
      for (int j = 0; j < 4; ++j) {
        int rl = WM + fm * 16 + crow0 + j;
        Cout[(size_t)prow[rl] * H0 + col] = v[j];
      }
    }
}

// ---------------- fused correction + MLP + LN + logit ----------------
__global__ __launch_bounds__(256) void k_mlp(
    const u32* __restrict__ pk,
    const int* __restrict__ user_idx, const int* __restrict__ item_idx,
    const float* __restrict__ Wu, const float* __restrict__ Wi,
    const float* __restrict__ u0, const float* __restrict__ u0b,
    const float* __restrict__ ir, const float* __restrict__ irb,
    const float* __restrict__ W1T, const float* __restrict__ b1,
    const float* __restrict__ g1, const float* __restrict__ be1,
    const float* __restrict__ W2T, const float* __restrict__ b2,
    const float* __restrict__ g2, const float* __restrict__ be2,
    const float* __restrict__ Wl, const float* __restrict__ bl,
    float* __restrict__ out) {
  __shared__ __attribute__((aligned(16))) float xl[16][H0];
  __shared__ __attribute__((aligned(16))) float h1l[16][H1];
  __shared__ int flagL[16], uL[16], iL[16];

  int tid = threadIdx.x, lane = tid & 63, wave = tid >> 6;
  int b0 = blockIdx.x * 16;

  if (tid < 16) {
    int b = b0 + tid;
    int uu = user_idx[b], ii = item_idx[b];
    uL[tid] = uu; iL[tid] = ii;
    u8 byte = ((const u8*)pk)[(size_t)uu * PKB + (ii >> 3)];
    flagL[tid] = (byte >> (ii & 7)) & 1;
  }
  __syncthreads();

  for (int idx = tid; idx < 16 * H0; idx += 256) {
    int rr = idx >> 8, h = idx & 255;
    size_t o = (size_t)(b0 + rr) * H0 + h;
    float x = u0[o] + u0b[o];
    if (flagL[rr]) x -= Wu[(size_t)h * N_ITEMS + iL[rr]];
    xl[rr][h] = x;
  }
  __syncthreads();

  float a0[16], a1[16];
  #pragma unroll
  for (int rr = 0; rr < 16; ++rr) { a0[rr] = 0.f; a1[rr] = 0.f; }
  for (int k4 = 0; k4 < H0 / 4; ++k4) {
    int k = k4 * 4;
    float w0a = W1T[(size_t)(k+0)*H1 + tid], w0b = W1T[(size_t)(k+0)*H1 + tid + 256];
    float w1a = W1T[(size_t)(k+1)*H1 + tid], w1b = W1T[(size_t)(k+1)*H1 + tid + 256];
    float w2a = W1T[(size_t)(k+2)*H1 + tid], w2b = W1T[(size_t)(k+2)*H1 + tid + 256];
    float w3a = W1T[(size_t)(k+3)*H1 + tid], w3b = W1T[(size_t)(k+3)*H1 + tid + 256];
    #pragma unroll
    for (int rr = 0; rr < 16; ++rr) {
      float4 x = *(const float4*)&xl[rr][k];
      a0[rr] += x.x * w0a + x.y * w1a + x.z * w2a + x.w * w3a;
      a1[rr] += x.x * w0b + x.y * w1b + x.z * w2b + x.w * w3b;
    }
  }
  #pragma unroll
  for (int rr = 0; rr < 16; ++rr) {
    h1l[rr][tid]       = a0[rr] + b1[tid];
    h1l[rr][tid + 256] = a1[rr] + b1[tid + 256];
  }
  __syncthreads();

  for (int rr = wave; rr < 16; rr += 4) {
    float s = 0.f;
    #pragma unroll
    for (int j = 0; j < 8; ++j) s += h1l[rr][lane + 64 * j];
    #pragma unroll
    for (int off = 32; off; off >>= 1) s += __shfl_xor(s, off);
    float m = s * (1.f / H1);
    float v = 0.f;
    #pragma unroll
    for (int j = 0; j < 8; ++j) { float d = h1l[rr][lane + 64*j] - m; v += d * d; }
    #pragma unroll
    for (int off = 32; off; off >>= 1) v += __shfl_xor(v, off);
    float inv = rsqrtf(v * (1.f / H1) + 1e-5f);
    #pragma unroll
    for (int j = 0; j < 8; ++j) {
      int o = lane + 64 * j;
      float y = (h1l[rr][o] - m) * inv * g1[o] + be1[o];
      h1l[rr][o] = fmaxf(y, 0.f);
    }
  }
  __syncthreads();

  float a2[16];
  #pragma unroll
  for (int rr = 0; rr < 16; ++rr) a2[rr] = 0.f;
  for (int k4 = 0; k4 < H1 / 4; ++k4) {
    int k = k4 * 4;
    float w0 = W2T[(size_t)(k+0)*H2 + tid];
    float w1 = W2T[(size_t)(k+1)*H2 + tid];
    float w2 = W2T[(size_t)(k+2)*H2 + tid];
    float w3 = W2T[(size_t)(k+3)*H2 + tid];
    #pragma unroll
    for (int rr = 0; rr < 16; ++rr) {
      float4 x = *(const float4*)&h1l[rr][k];
      a2[rr] += x.x * w0 + x.y * w1 + x.z * w2 + x.w * w3;
    }
  }
  __syncthreads();
  #pragma unroll
  for (int rr = 0; rr < 16; ++rr) xl[rr][tid] = a2[rr] + b2[tid];
  __syncthreads();

  for (int rr = wave; rr < 16; rr += 4) {
    float s = 0.f;
    #pragma unroll
    for (int j = 0; j < 4; ++j) s += xl[rr][lane + 64 * j];
    #pragma unroll
    for (int off = 32; off; off >>= 1) s += __shfl_xor(s, off);
    float m = s * (1.f / H2);
    float v = 0.f;
    #pragma unroll
    for (int j = 0; j < 4; ++j) { float d = xl[rr][lane + 64*j] - m; v += d * d; }
    #pragma unroll
    for (int off = 32; off; off >>= 1) v += __shfl_xor(v, off);
    float inv = rsqrtf(v * (1.f / H2) + 1e-5f);
    #pragma unroll
    for (int j = 0; j < 4; ++j) {
      int o = lane + 64 * j;
      float y = (xl[rr][o] - m) * inv * g2[o] + be2[o];
      xl[rr][o] = fmaxf(y, 0.f);
    }
  }
  __syncthreads();

  for (int rr = wave; rr < 16; rr += 4) {
    int b = b0 + rr;
    int flg = flagL[rr], uu = uL[rr];
    float s = 0.f;
    #pragma unroll
    for (int j = 0; j < 4; ++j) {
      int h = lane + 64 * j;
      size_t o = (size_t)b * H0 + h;
      float irv = ir[o] + irb[o];
      if (flg) irv -= Wi[(size_t)h * N_USERS + uu];
      s += xl[rr][h] * irv * Wl[h];
    }
    #pragma unroll
    for (int off = 32; off; off >>= 1) s += __shfl_xor(s, off);
    if (lane == 0) out[b] = s + bl[0];
  }
}

extern "C" void kernel_launch(void* const* d_in, const int* in_sizes, int n_in,
                              void* d_out, int out_size, void* d_ws, size_t ws_size,
                              hipStream_t stream) {
  const int*   user_idx = (const int*)d_in[0];
  const int*   item_idx = (const int*)d_in[1];
  const u8*    inter    = (const u8*)d_in[2];
  const float* Wu  = (const float*)d_in[3];
  const float* Wi  = (const float*)d_in[4];
  const float* W1  = (const float*)d_in[5];
  const float* b1  = (const float*)d_in[6];
  const float* g1  = (const float*)d_in[7];
  const float* be1 = (const float*)d_in[8];
  const float* W2  = (const float*)d_in[9];
  const float* b2  = (const float*)d_in[10];
  const float* g2  = (const float*)d_in[11];
  const float* be2 = (const float*)d_in[12];
  const float* Wl  = (const float*)d_in[13];
  const float* bl  = (const float*)d_in[14];
  float* out = (float*)d_out;

  char* ws = (char*)d_ws;
  size_t off = 0;
  auto alloc = [&](size_t bytes) {
    size_t o = off;
    off = (off + bytes + 255) & ~(size_t)255;
    return o;
  };
  int*   flag = (int*)  (ws + alloc(4));
  u32*   pkF  = (u32*)  (ws + alloc((size_t)(NWF + 64) * 4));
  u32*   pk   = (u32*)  (ws + alloc((size_t)N_USERS * PKB));
  u32*   pkT  = (u32*)  (ws + alloc((size_t)N_ITEMS * PKB));
  u16*   Wub  = (u16*)  (ws + alloc((size_t)H0 * N_ITEMS * 2));
  u16*   Wib  = (u16*)  (ws + alloc((size_t)H0 * N_USERS * 2));
  float* W1T  = (float*)(ws + alloc((size_t)H0 * H1 * 4));
  float* W2T  = (float*)(ws + alloc((size_t)H1 * H2 * 4));
  float* u0   = (float*)(ws + alloc((size_t)HB * H0 * 4));
  float* u0b  = (float*)(ws + alloc((size_t)HB * H0 * 4));
  float* ir   = (float*)(ws + alloc((size_t)HB * H0 * 4));
  float* irb  = (float*)(ws + alloc((size_t)HB * H0 * 4));
  int*   perm = (int*)  (ws + alloc((size_t)HB * 4));

  k_detect<<<1, 256, 0, stream>>>(inter, flag);
  k_packF<<<3072, 256, 0, stream>>>(inter, pkF, flag);
  k_realign<<<N_USERS, 256, 0, stream>>>(pkF, pk);
  k_bitT<<<1600, 256, 0, stream>>>(pk, pkT);
  k_convert2<<<1024, 256, 0, stream>>>(Wu, Wi, Wub, Wib);
  k_transpose2<<<256, 256, 0, stream>>>(W1, W1T, W2, W2T);
  k_sort<<<1, 1024, 0, stream>>>(item_idx, perm);
  k_gemm<<<1024, 256, 0, stream>>>(pk, pkT, user_idx, item_idx, perm, Wub, Wib,
                                   u0, u0b, ir, irb);
  k_mlp<<<256, 256, 0, stream>>>(pk, user_idx, item_idx, Wu, Wi, u0, u0b, ir, irb,
                                 W1T, b1, g1, be1, W2T, b2, g2, be2, Wl, bl, out);
}

// Round 18
// 630.007 us; speedup vs baseline: 3.5414x; 3.5414x over previous
//
#include <hip/hip_runtime.h>

#define N_USERS 20000
#define N_ITEMS 20000
#define NI1     20001      // row stride (elements) of interactions
#define HB      4096       // batch
#define H0      256
#define H1      512
#define H2      256
#define PKW     632        // u32 words per packed row (625 data + 7 zero pad)
#define PKB     (PKW*4)    // 2528 bytes per packed row
#define NWF     12501251   // flat words: ceil(20001*20001 / 32)
#define PADN    20224      // padded weight row stride = PKW*32 bits

typedef unsigned short u16;
typedef unsigned char  u8;
typedef unsigned int   u32;
typedef unsigned long long u64;

typedef __attribute__((ext_vector_type(8))) __bf16 bf16x8;
typedef __attribute__((ext_vector_type(4))) float  f32x4;

__device__ __forceinline__ u16 f2bf(float f) {
  u32 u = __float_as_uint(f);
  u32 r = (u + 0x7FFFu + ((u >> 16) & 1u)) >> 16;   // RNE
  return (u16)r;
}

// async global->LDS, 16B per lane; lp must be wave-uniform base (lane*16 auto)
__device__ __forceinline__ void gload16(const u16* gp, u16* lp) {
  __builtin_amdgcn_global_load_lds(
      (const __attribute__((address_space(1))) u32*)gp,
      (__attribute__((address_space(3))) u32*)lp, 16, 0, 0);
}

// ---------------- detect interactions element layout ----------------
__global__ __launch_bounds__(256) void k_detect(const u8* __restrict__ inter,
                                                int* __restrict__ flag) {
  __shared__ u32 cnt[4];
  if (threadIdx.x < 4) cnt[threadIdx.x] = 0;
  __syncthreads();
  u32 loc0 = 0, loc1 = 0, loc2 = 0, loc3 = 0;
  for (int i = threadIdx.x; i < 16384; i += 256) {   // 64 KB scan
    u32 w = ((const u32*)inter)[i];
    loc0 += (w & 0x000000FFu) ? 1u : 0u;
    loc1 += (w & 0x0000FF00u) ? 1u : 0u;
    loc2 += (w & 0x00FF0000u) ? 1u : 0u;
    loc3 += (w & 0xFF000000u) ? 1u : 0u;
  }
  atomicAdd(&cnt[0], loc0); atomicAdd(&cnt[1], loc1);
  atomicAdd(&cnt[2], loc2); atomicAdd(&cnt[3], loc3);
  __syncthreads();
  if (threadIdx.x == 0) {
    int lay;
    if (cnt[1] != 0)      lay = 0;
    else if (cnt[0] != 0) lay = 1;
    else                  lay = 2;
    *flag = lay;
  }
}

// ---------------- flat bit-pack, wave-coalesced ----------------
__global__ __launch_bounds__(256) void k_packF(const u8* __restrict__ inter,
                                               u32* __restrict__ pkF,
                                               const int* __restrict__ flag) {
  int lay = *flag;
  __shared__ u32 nibs[4][8][64];
  const size_t TE = (size_t)NI1 * NI1;
  const int NG = (int)((TE + 8191) / 8192);
  int wave = threadIdx.x >> 6, lane = threadIdx.x & 63;
  const u32* base32 = (const u32*)inter;
  for (int g = blockIdx.x; g < NG; g += gridDim.x) {
    size_t E0 = (size_t)g * 8192 + (size_t)wave * 2048;
    bool full = ((size_t)(g + 1) * 8192) <= TE;
    if (lay != 0) {
      if (full) {
        #pragma unroll
        for (int t = 0; t < 8; ++t) {
          size_t e = E0 + (size_t)t * 256 + lane * 4;
          uint4 v = *(const uint4*)(base32 + e);
          nibs[wave][t][lane] = (v.x ? 1u : 0u) | (v.y ? 2u : 0u) |
                                (v.z ? 4u : 0u) | (v.w ? 8u : 0u);
        }
      } else {
        #pragma unroll
        for (int t = 0; t < 8; ++t) {
          size_t e = E0 + (size_t)t * 256 + lane * 4;
          u32 n = 0;
          #pragma unroll
          for (int c = 0; c < 4; ++c)
            if (e + c < TE && base32[e + c]) n |= 1u << c;
          nibs[wave][t][lane] = n;
        }
      }
    } else {
      #pragma unroll
      for (int t = 0; t < 8; ++t) {
        size_t e = E0 + (size_t)t * 256 + lane * 4;
        u32 n = 0;
        #pragma unroll
        for (int c = 0; c < 4; ++c)
          if (e + c < TE && inter[e + c]) n |= 1u << c;
        nibs[wave][t][lane] = n;
      }
    }
    __syncthreads();
    {
      int t = lane >> 3, j = lane & 7;
      u32 wrd = 0;
      #pragma unroll
      for (int k = 0; k < 8; ++k) wrd |= nibs[wave][t][8 * j + k] << (4 * k);
      size_t wg = (size_t)g * 256 + wave * 64 + lane;
      if (wg < NWF) pkF[wg] = wrd;
    }
    __syncthreads();
  }
}

// ---------------- realign: pk[r][w] = flat bits [r*20001 + w*32, +32) ----------------
__global__ __launch_bounds__(256) void k_realign(const u32* __restrict__ pkF,
                                                 u32* __restrict__ pk) {
  int r = blockIdx.x;
  int base = 625 * r + (r >> 5);
  int s = r & 31;
  for (int w = threadIdx.x; w < PKW; w += 256) {
    u32 val = 0;
    if (w < 625) {
      u32 lo = pkF[base + w];
      u32 hi = pkF[base + w + 1];
      val = s ? ((lo >> s) | (hi << (32 - s))) : lo;
    }
    pk[(size_t)r * PKW + w] = val;
  }
}

// ---------------- bit transpose: single shared buffer (34.8 KB) ----------------
#define HDSTEP(J, M)                                      \
  _Pragma("unroll")                                       \
  for (int k = 0; k < 32; ++k) if (!(k & J)) {            \
    u32 tt = (a[k] ^ (a[k | J] >> J)) & M;                \
    a[k] ^= tt; a[k | J] ^= tt << J;                      \
  }

__global__ __launch_bounds__(256) void k_bitT(const u32* __restrict__ pk,
                                              u32* __restrict__ pkT) {
  __shared__ u32 buf[512 * 17];   // in-layout [rloc][lw]; later out-layout [i][lw][lr]
  int t = threadIdx.x;
  int vt = blockIdx.x % 40, wt = blockIdx.x / 40;
  int v0 = vt * 16, wc0 = wt * 16;
  int lw = t & 15, lr = t >> 4;
  for (int ch = 0; ch < 32; ++ch) {
    int rloc = ch * 16 + lr;
    int R = v0 * 32 + rloc;
    int W = wc0 + lw;
    u32 val = 0;
    if (R < N_USERS && W < PKW) val = pk[(size_t)R * PKW + W];
    buf[rloc * 17 + lw] = val;
  }
  __syncthreads();
  u32 a[32];
  #pragma unroll
  for (int j = 0; j < 32; ++j) a[j] = buf[(lr * 32 + j) * 17 + lw];
  HDSTEP(16, 0x0000FFFFu)
  HDSTEP(8,  0x00FF00FFu)
  HDSTEP(4,  0x0F0F0F0Fu)
  HDSTEP(2,  0x33333333u)
  HDSTEP(1,  0x55555555u)
  __syncthreads();               // all in-layout reads complete before overwrite
  #pragma unroll
  for (int i = 0; i < 32; ++i) buf[(i * 16 + lw) * 17 + lr] = __brev(a[31 - i]);
  __syncthreads();
  for (int ch = 0; ch < 32; ++ch) {
    int rloc = ch * 16 + lr;
    int C = wc0 * 32 + rloc;
    int V = v0 + lw;
    if (C < N_ITEMS && V < PKW)
      pkT[(size_t)C * PKW + V] = buf[((rloc & 31) * 16 + (rloc >> 5)) * 17 + lw];
  }
}

// ---------------- f32 -> bf16 with padded row stride PADN ----------------
// grid 512: block = one output row (0..255 -> Wub, 256..511 -> Wib)
__global__ __launch_bounds__(256) void k_convert2p(const float* __restrict__ Wu,
                                                   const float* __restrict__ Wi,
                                                   u16* __restrict__ Wub,
                                                   u16* __restrict__ Wib) {
  int r = blockIdx.x;
  const float* src = (r < 256) ? Wu : Wi;
  u16* dst = (r < 256) ? Wub : Wib;
  int rr = r & 255;
  src += (size_t)rr * N_ITEMS;
  dst += (size_t)rr * PADN;
  for (int k8 = threadIdx.x * 8; k8 < PADN; k8 += 256 * 8) {
    u64 p = 0;
    if (k8 < N_ITEMS) {   // 20000 % 8 == 0: full or zero
      float4 v0 = *(const float4*)(src + k8);
      float4 v1 = *(const float4*)(src + k8 + 4);
      p = (u64)f2bf(v0.x) | ((u64)f2bf(v0.y) << 16) |
          ((u64)f2bf(v0.z) << 32) | ((u64)f2bf(v0.w) << 48);
      u64 q = (u64)f2bf(v1.x) | ((u64)f2bf(v1.y) << 16) |
              ((u64)f2bf(v1.z) << 32) | ((u64)f2bf(v1.w) << 48);
      ((u64*)(dst + k8))[0] = p;
      ((u64*)(dst + k8))[1] = q;
    } else {
      ((u64*)(dst + k8))[0] = 0;
      ((u64*)(dst + k8))[1] = 0;
    }
  }
}

// ---------------- f32 transpose for W1 and W2 in one launch ----------------
__global__ __launch_bounds__(256) void k_transpose2(const float* __restrict__ W1,
                                                    float* __restrict__ W1T,
                                                    const float* __restrict__ W2,
                                                    float* __restrict__ W2T) {
  __shared__ float tile[32][33];
  int bid = blockIdx.x;
  const float* in; float* out; int R, C, b;
  if (bid < 128) { in = W1; out = W1T; R = H1; C = H0; b = bid; }
  else           { in = W2; out = W2T; R = H2; C = H1; b = bid - 128; }
  int nbx = C >> 5;
  int bx = b % nbx, by = b / nbx;
  int c0 = bx * 32, r0 = by * 32;
  int lx = threadIdx.x & 31, ly = threadIdx.x >> 5;
  #pragma unroll
  for (int j = 0; j < 4; ++j)
    tile[ly + 8*j][lx] = in[(size_t)(r0 + ly + 8*j) * C + c0 + lx];
  __syncthreads();
  #pragma unroll
  for (int j = 0; j < 4; ++j)
    out[(size_t)(c0 + ly + 8*j) * R + r0 + lx] = tile[lx][ly + 8*j];
}

// ---------------- counting sort of batch rows by item_idx ----------------
__global__ __launch_bounds__(1024) void k_sort(const int* __restrict__ item_idx,
                                               int* __restrict__ perm) {
  __shared__ u32 cnt[N_ITEMS];     // 80 KB
  __shared__ u32 tsum[1024];
  int t = threadIdx.x;
  for (int i = t; i < N_ITEMS; i += 1024) cnt[i] = 0;
  __syncthreads();
  for (int b = t; b < HB; b += 1024) atomicAdd(&cnt[item_idx[b]], 1u);
  __syncthreads();
  u32 s = 0;
  int base = t * 20;
  for (int j = 0; j < 20; ++j) { int i = base + j; if (i < N_ITEMS) s += cnt[i]; }
  tsum[t] = s;
  __syncthreads();
  for (int off = 1; off < 1024; off <<= 1) {
    u32 v = (t >= off) ? tsum[t - off] : 0u;
    __syncthreads();
    tsum[t] += v;
    __syncthreads();
  }
  u32 run = tsum[t] - s;  // exclusive prefix
  for (int j = 0; j < 20; ++j) {
    int i = base + j;
    if (i < N_ITEMS) { u32 c = cnt[i]; cnt[i] = run; run += c; }
  }
  __syncthreads();
  for (int b = t; b < HB; b += 1024) {
    int v = item_idx[b];
    u32 pos = atomicAdd(&cnt[v], 1u);
    perm[pos] = b;
  }
}

// ---------------- packed-bit GEMM: global_load_lds B staging + dbuf ----------------
// tile 128(M) x 32(N), BK=256; 4 waves; K-split x2.
// B staged direct-to-LDS (linear dest, pre-swizzled global source); A bits in regs.
__global__ __launch_bounds__(256, 4) void k_gemm(
    const u32* __restrict__ pk, const u32* __restrict__ pkT,
    const int* __restrict__ user_idx, const int* __restrict__ item_idx,
    const int* __restrict__ perm,
    const u16* __restrict__ Wub, const u16* __restrict__ Wib,
    float* __restrict__ u0, float* __restrict__ u0b,
    float* __restrict__ ir, float* __restrict__ irb) {
  __shared__ __attribute__((aligned(16))) u16 Bls[2][32 * 256];  // 2 x 16 KB
  __shared__ __attribute__((aligned(16))) uint2 lut8[16];        // nibble -> 4 bf16
  __shared__ u32 pbase[128];
  __shared__ int prow[128];

  int bid = blockIdx.x;
  int kh = bid >> 9;
  int mode_item = (bid >> 8) & 1;
  int lid = bid & 255;
  int M0 = (lid >> 3) * 128;
  int N0 = (lid & 7) * 32;
  int tid = threadIdx.x;
  const u16* Wb = mode_item ? Wib : Wub;
  const u8* Pk = (const u8*)(mode_item ? pkT : pk);
  float* Cout = mode_item ? (kh ? irb : ir) : (kh ? u0b : u0);

  if (tid < 16) {
    u32 v = tid;
    lut8[tid].x = ((v & 1u) ? 0x3F80u : 0u) | ((v & 2u) ? 0x3F800000u : 0u);
    lut8[tid].y = ((v & 4u) ? 0x3F80u : 0u) | ((v & 8u) ? 0x3F800000u : 0u);
  }
  if (tid < 128) {
    int s = M0 + tid;
    if (mode_item) { int p = perm[s]; prow[tid] = p; pbase[tid] = (u32)item_idx[p] * PKB; }
    else           { prow[tid] = s;   pbase[tid] = (u32)user_idx[s] * PKB; }
  }
  __syncthreads();

  f32x4 acc[2][2];
  #pragma unroll
  for (int a = 0; a < 2; ++a)
    #pragma unroll
    for (int b = 0; b < 2; ++b)
      #pragma unroll
      for (int j = 0; j < 4; ++j) acc[a][b][j] = 0.f;

  int lane = tid & 63, wave = tid >> 6;
  int WM = wave * 32;
  int lrow = lane & 15;
  int lk8 = lane >> 4;            // 0..3
  int sh = lk8 * 8;

  u32 pb0 = pbase[WM + lrow];
  u32 pb1 = pbase[WM + 16 + lrow];

  // staging addressing: linear LDS slot id = tid + 256*i (16B each);
  // global source pre-swizzled: k-offset = (c8 ^ (n&7))*8
  const u16* gsrc[4];
  int ldso[4];
  #pragma unroll
  for (int i = 0; i < 4; ++i) {
    int id = tid + 256 * i;
    int n = id >> 5, c8 = id & 31;
    gsrc[i] = Wb + (size_t)(N0 + n) * PADN + (c8 ^ (n & 7)) * 8;
    ldso[i] = (wave * 64 + 256 * i) * 8;   // wave-uniform u16 offset
  }

  int k0_beg = kh ? 10240 : 0;
  int k0_end = kh ? 20224 : 10240;   // 40/39 iters; pad bits/cols are zero

  // ---- prologue: async-stage B(t0), load A(t0) regs ----
  #pragma unroll
  for (int i = 0; i < 4; ++i) gload16(gsrc[i] + k0_beg, &Bls[0][ldso[i]]);
  int bc0 = k0_beg >> 3;
  uint4 ca0l = *(const uint4*)(Pk + pb0 + bc0);
  uint4 ca0h = *(const uint4*)(Pk + pb0 + bc0 + 16);
  uint4 ca1l = *(const uint4*)(Pk + pb1 + bc0);
  uint4 ca1h = *(const uint4*)(Pk + pb1 + bc0 + 16);
  __syncthreads();   // drains vmcnt: B(t0) resident

  int cur = 0;
  for (int k0 = k0_beg; k0 < k0_end; k0 += 256) {
    int k1 = k0 + 256;
    bool more = k1 < k0_end;
    uint4 na0l, na0h, na1l, na1h;
    if (more) {
      #pragma unroll
      for (int i = 0; i < 4; ++i) gload16(gsrc[i] + k1, &Bls[cur ^ 1][ldso[i]]);
      int nbc = k1 >> 3;
      na0l = *(const uint4*)(Pk + pb0 + nbc);
      na0h = *(const uint4*)(Pk + pb0 + nbc + 16);
      na1l = *(const uint4*)(Pk + pb1 + nbc);
      na1h = *(const uint4*)(Pk + pb1 + nbc + 16);
    }
    u32 qw0[8] = {ca0l.x, ca0l.y, ca0l.z, ca0l.w, ca0h.x, ca0h.y, ca0h.z, ca0h.w};
    u32 qw1[8] = {ca1l.x, ca1l.y, ca1l.z, ca1l.w, ca1h.x, ca1h.y, ca1h.z, ca1h.w};
    #pragma unroll
    for (int kki = 0; kki < 8; ++kki) {
      u32 b0 = (qw0[kki] >> sh) & 0xFFu;
      u32 b1 = (qw1[kki] >> sh) & 0xFFu;
      union { u32 w[4]; bf16x8 v; } a0, a1;
      uint2 l0 = lut8[b0 & 15u], h0 = lut8[b0 >> 4];
      uint2 l1 = lut8[b1 & 15u], h1 = lut8[b1 >> 4];
      a0.w[0] = l0.x; a0.w[1] = l0.y; a0.w[2] = h0.x; a0.w[3] = h0.y;
      a1.w[0] = l1.x; a1.w[1] = l1.y; a1.w[2] = h1.x; a1.w[3] = h1.y;
      bf16x8 bfr[2];
      #pragma unroll
      for (int fn = 0; fn < 2; ++fn) {
        int n = fn * 16 + lrow;
        bfr[fn] = *(const bf16x8*)&Bls[cur][n * 256 + ((kki * 32 + sh) ^ ((n & 7) << 3))];
      }
      acc[0][0] = __builtin_amdgcn_mfma_f32_16x16x32_bf16(a0.v, bfr[0], acc[0][0], 0, 0, 0);
      acc[0][1] = __builtin_amdgcn_mfma_f32_16x16x32_bf16(a0.v, bfr[1], acc[0][1], 0, 0, 0);
      acc[1][0] = __builtin_amdgcn_mfma_f32_16x16x32_bf16(a1.v, bfr[0], acc[1][0], 0, 0, 0);
      acc[1][1] = __builtin_amdgcn_mfma_f32_16x16x32_bf16(a1.v, bfr[1], acc[1][1], 0, 0, 0);
    }
    if (more) { ca0l = na0l; ca0h = na0h; ca1l = na1l; ca1h = na1h; }
    __syncthreads();   // drains gload_lds for next buffer + protects reuse
    cur ^= 1;
  }

  int crow0 = (lane >> 4) * 4;
  int ccol = lane & 15;
  #pragma unroll
  for (int fm = 0; fm < 2; ++fm)
    #pragma unroll
    for (int fn = 0; fn < 2; ++fn) {
      f32x4 v = acc[fm][fn];
      int col = N0 + fn * 16 + ccol;
      #pragma unroll
      for (int j = 0; j < 4; ++j) {
        int rl = WM + fm * 16 + crow0 + j;
        Cout[(size_t)prow[rl] * H0 + col] = v[j];
      }
    }
}

// ---------------- fused correction + MLP + LN + logit ----------------
__global__ __launch_bounds__(256) void k_mlp(
    const u32* __restrict__ pk,
    const int* __restrict__ user_idx, const int* __restrict__ item_idx,
    const float* __restrict__ Wu, const float* __restrict__ Wi,
    const float* __restrict__ u0, const float* __restrict__ u0b,
    const float* __restrict__ ir, const float* __restrict__ irb,
    const float* __restrict__ W1T, const float* __restrict__ b1,
    const float* __restrict__ g1, const float* __restrict__ be1,
    const float* __restrict__ W2T, const float* __restrict__ b2,
    const float* __restrict__ g2, const float* __restrict__ be2,
    const float* __restrict__ Wl, const float* __restrict__ bl,
    float* __restrict__ out) {
  __shared__ __attribute__((aligned(16))) float xl[16][H0];
  __shared__ __attribute__((aligned(16))) float h1l[16][H1];
  __shared__ int flagL[16], uL[16], iL[16];

  int tid = threadIdx.x, lane = tid & 63, wave = tid >> 6;
  int b0 = blockIdx.x * 16;

  if (tid < 16) {
    int b = b0 + tid;
    int uu = user_idx[b], ii = item_idx[b];
    uL[tid] = uu; iL[tid] = ii;
    u8 byte = ((const u8*)pk)[(size_t)uu * PKB + (ii >> 3)];
    flagL[tid] = (byte >> (ii & 7)) & 1;
  }
  __syncthreads();

  for (int idx = tid; idx < 16 * H0; idx += 256) {
    int rr = idx >> 8, h = idx & 255;
    size_t o = (size_t)(b0 + rr) * H0 + h;
    float x = u0[o] + u0b[o];
    if (flagL[rr]) x -= Wu[(size_t)h * N_ITEMS + iL[rr]];
    xl[rr][h] = x;
  }
  __syncthreads();

  float a0[16], a1[16];
  #pragma unroll
  for (int rr = 0; rr < 16; ++rr) { a0[rr] = 0.f; a1[rr] = 0.f; }
  for (int k4 = 0; k4 < H0 / 4; ++k4) {
    int k = k4 * 4;
    float w0a = W1T[(size_t)(k+0)*H1 + tid], w0b = W1T[(size_t)(k+0)*H1 + tid + 256];
    float w1a = W1T[(size_t)(k+1)*H1 + tid], w1b = W1T[(size_t)(k+1)*H1 + tid + 256];
    float w2a = W1T[(size_t)(k+2)*H1 + tid], w2b = W1T[(size_t)(k+2)*H1 + tid + 256];
    float w3a = W1T[(size_t)(k+3)*H1 + tid], w3b = W1T[(size_t)(k+3)*H1 + tid + 256];
    #pragma unroll
    for (int rr = 0; rr < 16; ++rr) {
      float4 x = *(const float4*)&xl[rr][k];
      a0[rr] += x.x * w0a + x.y * w1a + x.z * w2a + x.w * w3a;
      a1[rr] += x.x * w0b + x.y * w1b + x.z * w2b + x.w * w3b;
    }
  }
  #pragma unroll
  for (int rr = 0; rr < 16; ++rr) {
    h1l[rr][tid]       = a0[rr] + b1[tid];
    h1l[rr][tid + 256] = a1[rr] + b1[tid + 256];
  }
  __syncthreads();

  for (int rr = wave; rr < 16; rr += 4) {
    float s = 0.f;
    #pragma unroll
    for (int j = 0; j < 8; ++j) s += h1l[rr][lane + 64 * j];
    #pragma unroll
    for (int off = 32; off; off >>= 1) s += __shfl_xor(s, off);
    float m = s * (1.f / H1);
    float v = 0.f;
    #pragma unroll
    for (int j = 0; j < 8; ++j) { float d = h1l[rr][lane + 64*j] - m; v += d * d; }
    #pragma unroll
    for (int off = 32; off; off >>= 1) v += __shfl_xor(v, off);
    float inv = rsqrtf(v * (1.f / H1) + 1e-5f);
    #pragma unroll
    for (int j = 0; j < 8; ++j) {
      int o = lane + 64 * j;
      float y = (h1l[rr][o] - m) * inv * g1[o] + be1[o];
      h1l[rr][o] = fmaxf(y, 0.f);
    }
  }
  __syncthreads();

  float a2[16];
  #pragma unroll
  for (int rr = 0; rr < 16; ++rr) a2[rr] = 0.f;
  for (int k4 = 0; k4 < H1 / 4; ++k4) {
    int k = k4 * 4;
    float w0 = W2T[(size_t)(k+0)*H2 + tid];
    float w1 = W2T[(size_t)(k+1)*H2 + tid];
    float w2 = W2T[(size_t)(k+2)*H2 + tid];
    float w3 = W2T[(size_t)(k+3)*H2 + tid];
    #pragma unroll
    for (int rr = 0; rr < 16; ++rr) {
      float4 x = *(const float4*)&h1l[rr][k];
      a2[rr] += x.x * w0 + x.y * w1 + x.z * w2 + x.w * w3;
    }
  }
  __syncthreads();
  #pragma unroll
  for (int rr = 0; rr < 16; ++rr) xl[rr][tid] = a2[rr] + b2[tid];
  __syncthreads();

  for (int rr = wave; rr < 16; rr += 4) {
    float s = 0.f;
    #pragma unroll
    for (int j = 0; j < 4; ++j) s += xl[rr][lane + 64 * j];
    #pragma unroll
    for (int off = 32; off; off >>= 1) s += __shfl_xor(s, off);
    float m = s * (1.f / H2);
    float v = 0.f;
    #pragma unroll
    for (int j = 0; j < 4; ++j) { float d = xl[rr][lane + 64*j] - m; v += d * d; }
    #pragma unroll
    for (int off = 32; off; off >>= 1) v += __shfl_xor(v, off);
    float inv = rsqrtf(v * (1.f / H2) + 1e-5f);
    #pragma unroll
    for (int j = 0; j < 4; ++j) {
      int o = lane + 64 * j;
      float y = (xl[rr][o] - m) * inv * g2[o] + be2[o];
      xl[rr][o] = fmaxf(y, 0.f);
    }
  }
  __syncthreads();

  for (int rr = wave; rr < 16; rr += 4) {
    int b = b0 + rr;
    int flg = flagL[rr], uu = uL[rr];
    float s = 0.f;
    #pragma unroll
    for (int j = 0; j < 4; ++j) {
      int h = lane + 64 * j;
      size_t o = (size_t)b * H0 + h;
      float irv = ir[o] + irb[o];
      if (flg) irv -= Wi[(size_t)h * N_USERS + uu];
      s += xl[rr][h] * irv * Wl[h];
    }
    #pragma unroll
    for (int off = 32; off; off >>= 1) s += __shfl_xor(s, off);
    if (lane == 0) out[b] = s + bl[0];
  }
}

extern "C" void kernel_launch(void* const* d_in, const int* in_sizes, int n_in,
                              void* d_out, int out_size, void* d_ws, size_t ws_size,
                              hipStream_t stream) {
  const int*   user_idx = (const int*)d_in[0];
  const int*   item_idx = (const int*)d_in[1];
  const u8*    inter    = (const u8*)d_in[2];
  const float* Wu  = (const float*)d_in[3];
  const float* Wi  = (const float*)d_in[4];
  const float* W1  = (const float*)d_in[5];
  const float* b1  = (const float*)d_in[6];
  const float* g1  = (const float*)d_in[7];
  const float* be1 = (const float*)d_in[8];
  const float* W2  = (const float*)d_in[9];
  const float* b2  = (const float*)d_in[10];
  const float* g2  = (const float*)d_in[11];
  const float* be2 = (const float*)d_in[12];
  const float* Wl  = (const float*)d_in[13];
  const float* bl  = (const float*)d_in[14];
  float* out = (float*)d_out;

  char* ws = (char*)d_ws;
  size_t off = 0;
  auto alloc = [&](size_t bytes) {
    size_t o = off;
    off = (off + bytes + 255) & ~(size_t)255;
    return o;
  };
  int*   flag = (int*)  (ws + alloc(4));
  u32*   pkF  = (u32*)  (ws + alloc((size_t)(NWF + 64) * 4));
  u32*   pk   = (u32*)  (ws + alloc((size_t)N_USERS * PKB));
  u32*   pkT  = (u32*)  (ws + alloc((size_t)N_ITEMS * PKB));
  u16*   Wub  = (u16*)  (ws + alloc((size_t)H0 * PADN * 2));
  u16*   Wib  = (u16*)  (ws + alloc((size_t)H0 * PADN * 2));
  float* W1T  = (float*)(ws + alloc((size_t)H0 * H1 * 4));
  float* W2T  = (float*)(ws + alloc((size_t)H1 * H2 * 4));
  float* u0   = (float*)(ws + alloc((size_t)HB * H0 * 4));
  float* u0b  = (float*)(ws + alloc((size_t)HB * H0 * 4));
  float* ir   = (float*)(ws + alloc((size_t)HB * H0 * 4));
  float* irb  = (float*)(ws + alloc((size_t)HB * H0 * 4));
  int*   perm = (int*)  (ws + alloc((size_t)HB * 4));

  k_detect<<<1, 256, 0, stream>>>(inter, flag);
  k_packF<<<3072, 256, 0, stream>>>(inter, pkF, flag);
  k_realign<<<N_USERS, 256, 0, stream>>>(pkF, pk);
  k_bitT<<<1600, 256, 0, stream>>>(pk, pkT);
  k_convert2p<<<512, 256, 0, stream>>>(Wu, Wi, Wub, Wib);
  k_transpose2<<<256, 256, 0, stream>>>(W1, W1T, W2, W2T);
  k_sort<<<1, 1024, 0, stream>>>(item_idx, perm);
  k_gemm<<<1024, 256, 0, stream>>>(pk, pkT, user_idx, item_idx, perm, Wub, Wib,
                                   u0, u0b, ir, irb);
  k_mlp<<<256, 256, 0, stream>>>(pk, user_idx, item_idx, Wu, Wi, u0, u0b, ir, irb,
                                 W1T, b1, g1, be1, W2T, b2, g2, be2, Wl, bl, out);
}

// Round 19
// 582.450 us; speedup vs baseline: 3.8305x; 1.0817x over previous
//
#include <hip/hip_runtime.h>

#define N_USERS 20000
#define N_ITEMS 20000
#define NI1     20001      // row stride (elements) of interactions
#define HB      4096       // batch
#define H0      256
#define H1      512
#define H2      256
#define PKW     632        // u32 words per packed row (625 data + 7 zero pad)
#define PKB     (PKW*4)    // 2528 bytes per packed row
#define NWF     12501251   // flat words: ceil(20001*20001 / 32)
#define PADN    20224      // padded weight row stride = PKW*32 bits

typedef unsigned short u16;
typedef unsigned char  u8;
typedef unsigned int   u32;
typedef unsigned long long u64;

typedef __attribute__((ext_vector_type(8))) __bf16 bf16x8;
typedef __attribute__((ext_vector_type(4))) float  f32x4;
typedef __attribute__((ext_vector_type(4))) u32    u32x4;

__device__ __forceinline__ u16 f2bf(float f) {
  u32 u = __float_as_uint(f);
  u32 r = (u + 0x7FFFu + ((u >> 16) & 1u)) >> 16;   // RNE
  return (u16)r;
}

// async global->LDS, 16B per lane; lp must be wave-uniform base (lane*16 auto)
__device__ __forceinline__ void gload16(const u16* gp, u16* lp) {
  __builtin_amdgcn_global_load_lds(
      (const __attribute__((address_space(1))) u32*)gp,
      (__attribute__((address_space(3))) u32*)lp, 16, 0, 0);
}

// ---------------- detect interactions element layout ----------------
__global__ __launch_bounds__(256) void k_detect(const u8* __restrict__ inter,
                                                int* __restrict__ flag) {
  __shared__ u32 cnt[4];
  if (threadIdx.x < 4) cnt[threadIdx.x] = 0;
  __syncthreads();
  u32 loc0 = 0, loc1 = 0, loc2 = 0, loc3 = 0;
  for (int i = threadIdx.x; i < 16384; i += 256) {   // 64 KB scan
    u32 w = ((const u32*)inter)[i];
    loc0 += (w & 0x000000FFu) ? 1u : 0u;
    loc1 += (w & 0x0000FF00u) ? 1u : 0u;
    loc2 += (w & 0x00FF0000u) ? 1u : 0u;
    loc3 += (w & 0xFF000000u) ? 1u : 0u;
  }
  atomicAdd(&cnt[0], loc0); atomicAdd(&cnt[1], loc1);
  atomicAdd(&cnt[2], loc2); atomicAdd(&cnt[3], loc3);
  __syncthreads();
  if (threadIdx.x == 0) {
    int lay;
    if (cnt[1] != 0)      lay = 0;
    else if (cnt[0] != 0) lay = 1;
    else                  lay = 2;
    *flag = lay;
  }
}

// ---------------- flat bit-pack, wave-coalesced, nontemporal reads ----------------
__global__ __launch_bounds__(256) void k_packF(const u8* __restrict__ inter,
                                               u32* __restrict__ pkF,
                                               const int* __restrict__ flag) {
  int lay = *flag;
  __shared__ u32 nibs[4][8][64];
  const size_t TE = (size_t)NI1 * NI1;
  const int NG = (int)((TE + 8191) / 8192);
  int wave = threadIdx.x >> 6, lane = threadIdx.x & 63;
  const u32* base32 = (const u32*)inter;
  for (int g = blockIdx.x; g < NG; g += gridDim.x) {
    size_t E0 = (size_t)g * 8192 + (size_t)wave * 2048;
    bool full = ((size_t)(g + 1) * 8192) <= TE;
    if (lay != 0) {
      if (full) {
        #pragma unroll
        for (int t = 0; t < 8; ++t) {
          size_t e = E0 + (size_t)t * 256 + lane * 4;
          u32x4 v = __builtin_nontemporal_load((const u32x4*)(base32 + e));
          nibs[wave][t][lane] = (v.x ? 1u : 0u) | (v.y ? 2u : 0u) |
                                (v.z ? 4u : 0u) | (v.w ? 8u : 0u);
        }
      } else {
        #pragma unroll
        for (int t = 0; t < 8; ++t) {
          size_t e = E0 + (size_t)t * 256 + lane * 4;
          u32 n = 0;
          #pragma unroll
          for (int c = 0; c < 4; ++c)
            if (e + c < TE && base32[e + c]) n |= 1u << c;
          nibs[wave][t][lane] = n;
        }
      }
    } else {
      #pragma unroll
      for (int t = 0; t < 8; ++t) {
        size_t e = E0 + (size_t)t * 256 + lane * 4;
        u32 n = 0;
        #pragma unroll
        for (int c = 0; c < 4; ++c)
          if (e + c < TE && inter[e + c]) n |= 1u << c;
        nibs[wave][t][lane] = n;
      }
    }
    __syncthreads();
    {
      int t = lane >> 3, j = lane & 7;
      u32 wrd = 0;
      #pragma unroll
      for (int k = 0; k < 8; ++k) wrd |= nibs[wave][t][8 * j + k] << (4 * k);
      size_t wg = (size_t)g * 256 + wave * 64 + lane;
      if (wg < NWF) pkF[wg] = wrd;
    }
    __syncthreads();
  }
}

// ---------------- realign: pk[r][w] = flat bits [r*20001 + w*32, +32) ----------------
__global__ __launch_bounds__(256) void k_realign(const u32* __restrict__ pkF,
                                                 u32* __restrict__ pk) {
  int r = blockIdx.x;
  int base = 625 * r + (r >> 5);
  int s = r & 31;
  for (int w = threadIdx.x; w < PKW; w += 256) {
    u32 val = 0;
    if (w < 625) {
      u32 lo = pkF[base + w];
      u32 hi = pkF[base + w + 1];
      val = s ? ((lo >> s) | (hi << (32 - s))) : lo;
    }
    pk[(size_t)r * PKW + w] = val;
  }
}

// ---------------- bit transpose: single shared buffer (34.8 KB) ----------------
#define HDSTEP(J, M)                                      \
  _Pragma("unroll")                                       \
  for (int k = 0; k < 32; ++k) if (!(k & J)) {            \
    u32 tt = (a[k] ^ (a[k | J] >> J)) & M;                \
    a[k] ^= tt; a[k | J] ^= tt << J;                      \
  }

__global__ __launch_bounds__(256) void k_bitT(const u32* __restrict__ pk,
                                              u32* __restrict__ pkT) {
  __shared__ u32 buf[512 * 17];
  int t = threadIdx.x;
  int vt = blockIdx.x % 40, wt = blockIdx.x / 40;
  int v0 = vt * 16, wc0 = wt * 16;
  int lw = t & 15, lr = t >> 4;
  for (int ch = 0; ch < 32; ++ch) {
    int rloc = ch * 16 + lr;
    int R = v0 * 32 + rloc;
    int W = wc0 + lw;
    u32 val = 0;
    if (R < N_USERS && W < PKW) val = pk[(size_t)R * PKW + W];
    buf[rloc * 17 + lw] = val;
  }
  __syncthreads();
  u32 a[32];
  #pragma unroll
  for (int j = 0; j < 32; ++j) a[j] = buf[(lr * 32 + j) * 17 + lw];
  HDSTEP(16, 0x0000FFFFu)
  HDSTEP(8,  0x00FF00FFu)
  HDSTEP(4,  0x0F0F0F0Fu)
  HDSTEP(2,  0x33333333u)
  HDSTEP(1,  0x55555555u)
  __syncthreads();
  #pragma unroll
  for (int i = 0; i < 32; ++i) buf[(i * 16 + lw) * 17 + lr] = __brev(a[31 - i]);
  __syncthreads();
  for (int ch = 0; ch < 32; ++ch) {
    int rloc = ch * 16 + lr;
    int C = wc0 * 32 + rloc;
    int V = v0 + lw;
    if (C < N_ITEMS && V < PKW)
      pkT[(size_t)C * PKW + V] = buf[((rloc & 31) * 16 + (rloc >> 5)) * 17 + lw];
  }
}

// ---------------- f32 -> bf16 with padded row stride PADN ----------------
__global__ __launch_bounds__(256) void k_convert2p(const float* __restrict__ Wu,
                                                   const float* __restrict__ Wi,
                                                   u16* __restrict__ Wub,
                                                   u16* __restrict__ Wib) {
  int r = blockIdx.x;
  const float* src = (r < 256) ? Wu : Wi;
  u16* dst = (r < 256) ? Wub : Wib;
  int rr = r & 255;
  src += (size_t)rr * N_ITEMS;
  dst += (size_t)rr * PADN;
  for (int k8 = threadIdx.x * 8; k8 < PADN; k8 += 256 * 8) {
    if (k8 < N_ITEMS) {   // 20000 % 8 == 0: full or zero
      float4 v0 = *(const float4*)(src + k8);
      float4 v1 = *(const float4*)(src + k8 + 4);
      u64 p = (u64)f2bf(v0.x) | ((u64)f2bf(v0.y) << 16) |
              ((u64)f2bf(v0.z) << 32) | ((u64)f2bf(v0.w) << 48);
      u64 q = (u64)f2bf(v1.x) | ((u64)f2bf(v1.y) << 16) |
              ((u64)f2bf(v1.z) << 32) | ((u64)f2bf(v1.w) << 48);
      ((u64*)(dst + k8))[0] = p;
      ((u64*)(dst + k8))[1] = q;
    } else {
      ((u64*)(dst + k8))[0] = 0;
      ((u64*)(dst + k8))[1] = 0;
    }
  }
}

// ---------------- f32 transpose for W1 and W2 in one launch ----------------
__global__ __launch_bounds__(256) void k_transpose2(const float* __restrict__ W1,
                                                    float* __restrict__ W1T,
                                                    const float* __restrict__ W2,
                                                    float* __restrict__ W2T) {
  __shared__ float tile[32][33];
  int bid = blockIdx.x;
  const float* in; float* out; int R, C, b;
  if (bid < 128) { in = W1; out = W1T; R = H1; C = H0; b = bid; }
  else           { in = W2; out = W2T; R = H2; C = H1; b = bid - 128; }
  int nbx = C >> 5;
  int bx = b % nbx, by = b / nbx;
  int c0 = bx * 32, r0 = by * 32;
  int lx = threadIdx.x & 31, ly = threadIdx.x >> 5;
  #pragma unroll
  for (int j = 0; j < 4; ++j)
    tile[ly + 8*j][lx] = in[(size_t)(r0 + ly + 8*j) * C + c0 + lx];
  __syncthreads();
  #pragma unroll
  for (int j = 0; j < 4; ++j)
    out[(size_t)(c0 + ly + 8*j) * R + r0 + lx] = tile[lx][ly + 8*j];
}

// ---------------- counting sort of batch rows by item_idx ----------------
__global__ __launch_bounds__(1024) void k_sort(const int* __restrict__ item_idx,
                                               int* __restrict__ perm) {
  __shared__ u32 cnt[N_ITEMS];     // 80 KB
  __shared__ u32 tsum[1024];
  int t = threadIdx.x;
  for (int i = t; i < N_ITEMS; i += 1024) cnt[i] = 0;
  __syncthreads();
  for (int b = t; b < HB; b += 1024) atomicAdd(&cnt[item_idx[b]], 1u);
  __syncthreads();
  u32 s = 0;
  int base = t * 20;
  for (int j = 0; j < 20; ++j) { int i = base + j; if (i < N_ITEMS) s += cnt[i]; }
  tsum[t] = s;
  __syncthreads();
  for (int off = 1; off < 1024; off <<= 1) {
    u32 v = (t >= off) ? tsum[t - off] : 0u;
    __syncthreads();
    tsum[t] += v;
    __syncthreads();
  }
  u32 run = tsum[t] - s;  // exclusive prefix
  for (int j = 0; j < 20; ++j) {
    int i = base + j;
    if (i < N_ITEMS) { u32 c = cnt[i]; cnt[i] = run; run += c; }
  }
  __syncthreads();
  for (int b = t; b < HB; b += 1024) {
    int v = item_idx[b];
    u32 pos = atomicAdd(&cnt[v], 1u);
    perm[pos] = b;
  }
}

// ---------------- packed-bit GEMM: BK=128, K-split x4, 6 blocks/CU ----------------
// tile 128(M) x 32(N); 4 waves; grid 2048; gload_lds B dbuf (2 x 8 KB).
__global__ __launch_bounds__(256, 6) void k_gemm(
    const u32* __restrict__ pk, const u32* __restrict__ pkT,
    const int* __restrict__ user_idx, const int* __restrict__ item_idx,
    const int* __restrict__ perm,
    const u16* __restrict__ Wub, const u16* __restrict__ Wib,
    float* __restrict__ u0a, float* __restrict__ u0b,
    float* __restrict__ u0c, float* __restrict__ u0d,
    float* __restrict__ ira, float* __restrict__ irb,
    float* __restrict__ irc, float* __restrict__ ird) {
  __shared__ __attribute__((aligned(16))) u16 Bls[2][32 * 128];  // 2 x 8 KB
  __shared__ __attribute__((aligned(16))) uint2 lut8[16];        // nibble -> 4 bf16
  __shared__ u32 pbase[128];
  __shared__ int prow[128];

  int bid = blockIdx.x;
  int kh = bid >> 9;                 // 0..3
  int mode_item = (bid >> 8) & 1;
  int lid = bid & 255;
  int M0 = (lid >> 3) * 128;
  int N0 = (lid & 7) * 32;
  int tid = threadIdx.x;
  const u16* Wb = mode_item ? Wib : Wub;
  const u8* Pk = (const u8*)(mode_item ? pkT : pk);
  float* Cout;
  if (mode_item) Cout = (kh == 0) ? ira : (kh == 1) ? irb : (kh == 2) ? irc : ird;
  else           Cout = (kh == 0) ? u0a : (kh == 1) ? u0b : (kh == 2) ? u0c : u0d;

  if (tid < 16) {
    u32 v = tid;
    lut8[tid].x = ((v & 1u) ? 0x3F80u : 0u) | ((v & 2u) ? 0x3F800000u : 0u);
    lut8[tid].y = ((v & 4u) ? 0x3F80u : 0u) | ((v & 8u) ? 0x3F800000u : 0u);
  }
  if (tid < 128) {
    int s = M0 + tid;
    if (mode_item) { int p = perm[s]; prow[tid] = p; pbase[tid] = (u32)item_idx[p] * PKB; }
    else           { prow[tid] = s;   pbase[tid] = (u32)user_idx[s] * PKB; }
  }
  __syncthreads();

  f32x4 acc[2][2];
  #pragma unroll
  for (int a = 0; a < 2; ++a)
    #pragma unroll
    for (int b = 0; b < 2; ++b)
      #pragma unroll
      for (int j = 0; j < 4; ++j) acc[a][b][j] = 0.f;

  int lane = tid & 63, wave = tid >> 6;
  int WM = wave * 32;
  int lrow = lane & 15;
  int lk8 = lane >> 4;            // 0..3
  int sh = lk8 * 8;

  u32 pb0 = pbase[WM + lrow];
  u32 pb1 = pbase[WM + 16 + lrow];

  // staging: 2 slots/thread; linear LDS; pre-swizzled global source
  const u16* gsrc[2];
  int ldso[2];
  #pragma unroll
  for (int i = 0; i < 2; ++i) {
    int id = tid + 256 * i;
    int n = id >> 4, c8 = id & 15;
    gsrc[i] = Wb + (size_t)(N0 + n) * PADN + (c8 ^ (n & 7)) * 8;
    ldso[i] = (wave * 64 + 256 * i) * 8;   // wave-uniform u16 offset
  }

  int k0_beg = kh * 5120;
  int k0_end = (kh == 3) ? 20224 : (k0_beg + 5120);   // 40/40/40/38 iters

  // ---- prologue ----
  #pragma unroll
  for (int i = 0; i < 2; ++i) gload16(gsrc[i] + k0_beg, &Bls[0][ldso[i]]);
  uint4 ca0 = *(const uint4*)(Pk + pb0 + (k0_beg >> 3));
  uint4 ca1 = *(const uint4*)(Pk + pb1 + (k0_beg >> 3));
  __syncthreads();

  int cur = 0;
  for (int k0 = k0_beg; k0 < k0_end; k0 += 128) {
    int k1 = k0 + 128;
    bool more = k1 < k0_end;
    uint4 na0, na1;
    if (more) {
      #pragma unroll
      for (int i = 0; i < 2; ++i) gload16(gsrc[i] + k1, &Bls[cur ^ 1][ldso[i]]);
      na0 = *(const uint4*)(Pk + pb0 + (k1 >> 3));
      na1 = *(const uint4*)(Pk + pb1 + (k1 >> 3));
    }
    u32 qw0[4] = {ca0.x, ca0.y, ca0.z, ca0.w};
    u32 qw1[4] = {ca1.x, ca1.y, ca1.z, ca1.w};
    #pragma unroll
    for (int kki = 0; kki < 4; ++kki) {
      u32 b0 = (qw0[kki] >> sh) & 0xFFu;
      u32 b1 = (qw1[kki] >> sh) & 0xFFu;
      union { u32 w[4]; bf16x8 v; } a0, a1;
      uint2 l0 = lut8[b0 & 15u], h0 = lut8[b0 >> 4];
      uint2 l1 = lut8[b1 & 15u], h1 = lut8[b1 >> 4];
      a0.w[0] = l0.x; a0.w[1] = l0.y; a0.w[2] = h0.x; a0.w[3] = h0.y;
      a1.w[0] = l1.x; a1.w[1] = l1.y; a1.w[2] = h1.x; a1.w[3] = h1.y;
      bf16x8 bfr[2];
      #pragma unroll
      for (int fn = 0; fn < 2; ++fn) {
        int n = fn * 16 + lrow;
        bfr[fn] = *(const bf16x8*)&Bls[cur][n * 128 + ((kki * 32 + sh) ^ ((n & 7) << 3))];
      }
      acc[0][0] = __builtin_amdgcn_mfma_f32_16x16x32_bf16(a0.v, bfr[0], acc[0][0], 0, 0, 0);
      acc[0][1] = __builtin_amdgcn_mfma_f32_16x16x32_bf16(a0.v, bfr[1], acc[0][1], 0, 0, 0);
      acc[1][0] = __builtin_amdgcn_mfma_f32_16x16x32_bf16(a1.v, bfr[0], acc[1][0], 0, 0, 0);
      acc[1][1] = __builtin_amdgcn_mfma_f32_16x16x32_bf16(a1.v, bfr[1], acc[1][1], 0, 0, 0);
    }
    if (more) { ca0 = na0; ca1 = na1; }
    __syncthreads();
    cur ^= 1;
  }

  int crow0 = (lane >> 4) * 4;
  int ccol = lane & 15;
  #pragma unroll
  for (int fm = 0; fm < 2; ++fm)
    #pragma unroll
    for (int fn = 0; fn < 2; ++fn) {
      f32x4 v = acc[fm][fn];
      int col = N0 + fn * 16 + ccol;
      #pragma unroll
      for (int j = 0; j < 4; ++j) {
        int rl = WM + fm * 16 + crow0 + j;
        Cout[(size_t)prow[rl] * H0 + col] = v[j];
      }
    }
}

// ---------------- fused correction + MLP + LN + logit ----------------
__global__ __launch_bounds__(256) void k_mlp(
    const u32* __restrict__ pk,
    const int* __restrict__ user_idx, const int* __restrict__ item_idx,
    const float* __restrict__ Wu, const float* __restrict__ Wi,
    const float* __restrict__ u0a, const float* __restrict__ u0b,
    const float* __restrict__ u0c, const float* __restrict__ u0d,
    const float* __restrict__ ira, const float* __restrict__ irb,
    const float* __restrict__ irc, const float* __restrict__ ird,
    const float* __restrict__ W1T, const float* __restrict__ b1,
    const float* __restrict__ g1, const float* __restrict__ be1,
    const float* __restrict__ W2T, const float* __restrict__ b2,
    const float* __restrict__ g2, const float* __restrict__ be2,
    const float* __restrict__ Wl, const float* __restrict__ bl,
    float* __restrict__ out) {
  __shared__ __attribute__((aligned(16))) float xl[16][H0];
  __shared__ __attribute__((aligned(16))) float h1l[16][H1];
  __shared__ int flagL[16], uL[16], iL[16];

  int tid = threadIdx.x, lane = tid & 63, wave = tid >> 6;
  int b0 = blockIdx.x * 16;

  if (tid < 16) {
    int b = b0 + tid;
    int uu = user_idx[b], ii = item_idx[b];
    uL[tid] = uu; iL[tid] = ii;
    u8 byte = ((const u8*)pk)[(size_t)uu * PKB + (ii >> 3)];
    flagL[tid] = (byte >> (ii & 7)) & 1;
  }
  __syncthreads();

  for (int idx = tid; idx < 16 * H0; idx += 256) {
    int rr = idx >> 8, h = idx & 255;
    size_t o = (size_t)(b0 + rr) * H0 + h;
    float x = (u0a[o] + u0b[o]) + (u0c[o] + u0d[o]);
    if (flagL[rr]) x -= Wu[(size_t)h * N_ITEMS + iL[rr]];
    xl[rr][h] = x;
  }
  __syncthreads();

  float a0[16], a1[16];
  #pragma unroll
  for (int rr = 0; rr < 16; ++rr) { a0[rr] = 0.f; a1[rr] = 0.f; }
  for (int k4 = 0; k4 < H0 / 4; ++k4) {
    int k = k4 * 4;
    float w0a = W1T[(size_t)(k+0)*H1 + tid], w0b = W1T[(size_t)(k+0)*H1 + tid + 256];
    float w1a = W1T[(size_t)(k+1)*H1 + tid], w1b = W1T[(size_t)(k+1)*H1 + tid + 256];
    float w2a = W1T[(size_t)(k+2)*H1 + tid], w2b = W1T[(size_t)(k+2)*H1 + tid + 256];
    float w3a = W1T[(size_t)(k+3)*H1 + tid], w3b = W1T[(size_t)(k+3)*H1 + tid + 256];
    #pragma unroll
    for (int rr = 0; rr < 16; ++rr) {
      float4 x = *(const float4*)&xl[rr][k];
      a0[rr] += x.x * w0a + x.y * w1a + x.z * w2a + x.w * w3a;
      a1[rr] += x.x * w0b + x.y * w1b + x.z * w2b + x.w * w3b;
    }
  }
  #pragma unroll
  for (int rr = 0; rr < 16; ++rr) {
    h1l[rr][tid]       = a0[rr] + b1[tid];
    h1l[rr][tid + 256] = a1[rr] + b1[tid + 256];
  }
  __syncthreads();

  for (int rr = wave; rr < 16; rr += 4) {
    float s = 0.f;
    #pragma unroll
    for (int j = 0; j < 8; ++j) s += h1l[rr][lane + 64 * j];
    #pragma unroll
    for (int off = 32; off; off >>= 1) s += __shfl_xor(s, off);
    float m = s * (1.f / H1);
    float v = 0.f;
    #pragma unroll
    for (int j = 0; j < 8; ++j) { float d = h1l[rr][lane + 64*j] - m; v += d * d; }
    #pragma unroll
    for (int off = 32; off; off >>= 1) v += __shfl_xor(v, off);
    float inv = rsqrtf(v * (1.f / H1) + 1e-5f);
    #pragma unroll
    for (int j = 0; j < 8; ++j) {
      int o = lane + 64 * j;
      float y = (h1l[rr][o] - m) * inv * g1[o] + be1[o];
      h1l[rr][o] = fmaxf(y, 0.f);
    }
  }
  __syncthreads();

  float a2[16];
  #pragma unroll
  for (int rr = 0; rr < 16; ++rr) a2[rr] = 0.f;
  for (int k4 = 0; k4 < H1 / 4; ++k4) {
    int k = k4 * 4;
    float w0 = W2T[(size_t)(k+0)*H2 + tid];
    float w1 = W2T[(size_t)(k+1)*H2 + tid];
    float w2 = W2T[(size_t)(k+2)*H2 + tid];
    float w3 = W2T[(size_t)(k+3)*H2 + tid];
    #pragma unroll
    for (int rr = 0; rr < 16; ++rr) {
      float4 x = *(const float4*)&h1l[rr][k];
      a2[rr] += x.x * w0 + x.y * w1 + x.z * w2 + x.w * w3;
    }
  }
  __syncthreads();
  #pragma unroll
  for (int rr = 0; rr < 16; ++rr) xl[rr][tid] = a2[rr] + b2[tid];
  __syncthreads();

  for (int rr = wave; rr < 16; rr += 4) {
    float s = 0.f;
    #pragma unroll
    for (int j = 0; j < 4; ++j) s += xl[rr][lane + 64 * j];
    #pragma unroll
    for (int off = 32; off; off >>= 1) s += __shfl_xor(s, off);
    float m = s * (1.f / H2);
    float v = 0.f;
    #pragma unroll
    for (int j = 0; j < 4; ++j) { float d = xl[rr][lane + 64*j] - m; v += d * d; }
    #pragma unroll
    for (int off = 32; off; off >>= 1) v += __shfl_xor(v, off);
    float inv = rsqrtf(v * (1.f / H2) + 1e-5f);
    #pragma unroll
    for (int j = 0; j < 4; ++j) {
      int o = lane + 64 * j;
      float y = (xl[rr][o] - m) * inv * g2[o] + be2[o];
      xl[rr][o] = fmaxf(y, 0.f);
    }
  }
  __syncthreads();

  for (int rr = wave; rr < 16; rr += 4) {
    int b = b0 + rr;
    int flg = flagL[rr], uu = uL[rr];
    float s = 0.f;
    #pragma unroll
    for (int j = 0; j < 4; ++j) {
      int h = lane + 64 * j;
      size_t o = (size_t)b * H0 + h;
      float irv = (ira[o] + irb[o]) + (irc[o] + ird[o]);
      if (flg) irv -= Wi[(size_t)h * N_USERS + uu];
      s += xl[rr][h] * irv * Wl[h];
    }
    #pragma unroll
    for (int off = 32; off; off >>= 1) s += __shfl_xor(s, off);
    if (lane == 0) out[b] = s + bl[0];
  }
}

extern "C" void kernel_launch(void* const* d_in, const int* in_sizes, int n_in,
                              void* d_out, int out_size, void* d_ws, size_t ws_size,
                              hipStream_t stream) {
  const int*   user_idx = (const int*)d_in[0];
  const int*   item_idx = (const int*)d_in[1];
  const u8*    inter    = (const u8*)d_in[2];
  const float* Wu  = (const float*)d_in[3];
  const float* Wi  = (const float*)d_in[4];
  const float* W1  = (const float*)d_in[5];
  const float* b1  = (const float*)d_in[6];
  const float* g1  = (const float*)d_in[7];
  const float* be1 = (const float*)d_in[8];
  const float* W2  = (const float*)d_in[9];
  const float* b2  = (const float*)d_in[10];
  const float* g2  = (const float*)d_in[11];
  const float* be2 = (const float*)d_in[12];
  const float* Wl  = (const float*)d_in[13];
  const float* bl  = (const float*)d_in[14];
  float* out = (float*)d_out;

  char* ws = (char*)d_ws;
  size_t off = 0;
  auto alloc = [&](size_t bytes) {
    size_t o = off;
    off = (off + bytes + 255) & ~(size_t)255;
    return o;
  };
  int*   flag = (int*)  (ws + alloc(4));
  u32*   pkF  = (u32*)  (ws + alloc((size_t)(NWF + 64) * 4));
  u32*   pk   = (u32*)  (ws + alloc((size_t)N_USERS * PKB));
  u32*   pkT  = (u32*)  (ws + alloc((size_t)N_ITEMS * PKB));
  u16*   Wub  = (u16*)  (ws + alloc((size_t)H0 * PADN * 2));
  u16*   Wib  = (u16*)  (ws + alloc((size_t)H0 * PADN * 2));
  float* W1T  = (float*)(ws + alloc((size_t)H0 * H1 * 4));
  float* W2T  = (float*)(ws + alloc((size_t)H1 * H2 * 4));
  float* u0a  = (float*)(ws + alloc((size_t)HB * H0 * 4));
  float* u0b  = (float*)(ws + alloc((size_t)HB * H0 * 4));
  float* u0c  = (float*)(ws + alloc((size_t)HB * H0 * 4));
  float* u0d  = (float*)(ws + alloc((size_t)HB * H0 * 4));
  float* ira  = (float*)(ws + alloc((size_t)HB * H0 * 4));
  float* irb  = (float*)(ws + alloc((size_t)HB * H0 * 4));
  float* irc  = (float*)(ws + alloc((size_t)HB * H0 * 4));
  float* ird  = (float*)(ws + alloc((size_t)HB * H0 * 4));
  int*   perm = (int*)  (ws + alloc((size_t)HB * 4));

  k_detect<<<1, 256, 0, stream>>>(inter, flag);
  k_packF<<<3072, 256, 0, stream>>>(inter, pkF, flag);
  k_realign<<<N_USERS, 256, 0, stream>>>(pkF, pk);
  k_bitT<<<1600, 256, 0, stream>>>(pk, pkT);
  k_convert2p<<<512, 256, 0, stream>>>(Wu, Wi, Wub, Wib);
  k_transpose2<<<256, 256, 0, stream>>>(W1, W1T, W2, W2T);
  k_sort<<<1, 1024, 0, stream>>>(item_idx, perm);
  k_gemm<<<2048, 256, 0, stream>>>(pk, pkT, user_idx, item_idx, perm, Wub, Wib,
                                   u0a, u0b, u0c, u0d, ira, irb, irc, ird);
  k_mlp<<<256, 256, 0, stream>>>(pk, user_idx, item_idx, Wu, Wi,
                                 u0a, u0b, u0c, u0d, ira, irb, irc, ird,
                                 W1T, b1, g1, be1, W2T, b2, g2, be2, Wl, bl, out);
}